// Round 4
// baseline (1236.885 us; speedup 1.0000x reference)
//
#include <hip/hip_runtime.h>
#include <hip/hip_bf16.h>

// GCN 2-layer, bucket-partition + LDS-accumulate formulation:
//   h1 = bf16( bf16(x) @ bf16(W1) )     (MFMA 16x16x32, [N,64])
//   partition edges into buckets of 256 dst nodes (dst>>8), LDS-staged runs
//   gather1: per bucket, LDS fp32 accum of h1[src]*w; relu(+b1) @ W2 -> h2 bf16
//   gather2: per bucket, LDS fp32 accum of h2[src]*w; +b2 -> out f32

typedef unsigned short u16;
typedef short short8 __attribute__((ext_vector_type(8)));
typedef float floatx4 __attribute__((ext_vector_type(4)));

static __device__ __forceinline__ float bf2f(u16 v) {
    return __uint_as_float(((unsigned int)v) << 16);
}
static __device__ __forceinline__ u16 f2bf(float f) {
    unsigned int u = __float_as_uint(f);
    return (u16)((u + 0x7fff + ((u >> 16) & 1)) >> 16);   // RNE
}

#define F4C(v, j) ((j)==0?(v).x:((j)==1?(v).y:((j)==2?(v).z:(v).w)))

// ---------------- g1_mfma: h1 = x @ W1 via bf16 MFMA ----------------
__global__ __launch_bounds__(256, 4) void g1_mfma(
    const float* __restrict__ x, const float* __restrict__ W1,
    u16* __restrict__ h1, int N)
{
    __shared__ __align__(16) u16 xs[64][136];
    __shared__ __align__(16) u16 wf[4][4][64][8];      // [ntile][step][lane][j]
    const int tid  = threadIdx.x;
    const int row0 = blockIdx.x * 64;

    {   // stage W1 (128x64 f32) -> bf16, swizzled to B-fragment order
        const float4* W4 = (const float4*)W1;
        #pragma unroll
        for (int i = 0; i < 8; i++) {
            int idx = tid + i*256;
            int k = idx >> 4, n4 = (idx & 15) * 4;
            float4 v = W4[idx];
            int step = k >> 5, klane = (k >> 3) & 3, j = k & 7;
            #pragma unroll
            for (int c = 0; c < 4; c++) {
                int n = n4 + c;
                wf[n >> 4][step][klane*16 + (n & 15)][j] = f2bf(F4C(v, c));
            }
        }
    }
    {   // stage x tile -> bf16
        const float4* x4 = (const float4*)x;
        #pragma unroll
        for (int i = 0; i < 8; i++) {
            int idx = tid + i*256;
            int r = idx >> 5, kc = idx & 31;
            int gr = row0 + r;
            float4 v = make_float4(0.f,0.f,0.f,0.f);
            if (gr < N) v = x4[gr*32 + kc];
            ushort4 o;
            o.x = f2bf(v.x); o.y = f2bf(v.y); o.z = f2bf(v.z); o.w = f2bf(v.w);
            *(ushort4*)&xs[r][kc*4] = o;
        }
    }
    __syncthreads();

    const int wave = tid >> 6, lane = tid & 63;
    const int m = lane & 15, quad = lane >> 4;
    const int rw = wave * 16;

    floatx4 acc[4] = {(floatx4)(0.f), (floatx4)(0.f), (floatx4)(0.f), (floatx4)(0.f)};
    #pragma unroll
    for (int step = 0; step < 4; step++) {
        short8 a = *(const short8*)&xs[rw + m][step*32 + quad*8];
        #pragma unroll
        for (int nt = 0; nt < 4; nt++) {
            short8 b = *(const short8*)&wf[nt][step][lane][0];
            acc[nt] = __builtin_amdgcn_mfma_f32_16x16x32_bf16(a, b, acc[nt], 0, 0, 0);
        }
    }
    #pragma unroll
    for (int nt = 0; nt < 4; nt++) {
        #pragma unroll
        for (int r = 0; r < 4; r++) {
            int gr = row0 + rw + quad*4 + r;
            if (gr < N) h1[(size_t)gr*64 + nt*16 + m] = f2bf(acc[nt][r]);
        }
    }
}

// ---------------- bucket histogram (LDS pre-aggregated) ----------------
__global__ __launch_bounds__(256) void bucket_hist(
    const int* __restrict__ dst, int* __restrict__ counts, int E)
{
    __shared__ int h[512];
    const int tid = threadIdx.x;
    for (int i = tid; i < 512; i += 256) h[i] = 0;
    __syncthreads();
    int base = blockIdx.x * 1024;
    #pragma unroll
    for (int k = 0; k < 4; k++) {
        int i = base + k*256 + tid;
        if (i < E) atomicAdd(&h[dst[i] >> 8], 1);
    }
    __syncthreads();
    for (int i = tid; i < 512; i += 256)
        if (h[i]) atomicAdd(&counts[i], h[i]);
}

// ---------------- bucket scan (1 block, 512 threads) ----------------
__global__ __launch_bounds__(512) void bucket_scan(
    const int* __restrict__ counts, int* __restrict__ boff,
    int* __restrict__ gcursor, int nb)
{
    __shared__ int A[512], B[512];
    const int t = threadIdx.x;
    int v = (t < nb) ? counts[t] : 0;
    A[t] = v;
    __syncthreads();
    int* cur = A; int* nxt = B;
    for (int off = 1; off < 512; off <<= 1) {
        nxt[t] = cur[t] + ((t >= off) ? cur[t - off] : 0);
        __syncthreads();
        int* tmp = cur; cur = nxt; nxt = tmp;
    }
    int ex = cur[t] - v;           // exclusive
    if (t <= nb) boff[t] = ex;     // boff[nb] == E
    if (t < nb)  gcursor[t] = ex;
}

// ---------------- partition: LDS-staged scatter into bucket runs ----------
// entry: x = src | (dst&255)<<24 ; y = w bits
#define CHUNK 4096
__global__ __launch_bounds__(256, 3) void partition_kernel(
    const int* __restrict__ src, const int* __restrict__ dst,
    const float* __restrict__ w, int* __restrict__ gcursor,
    int2* __restrict__ es, int E)
{
    __shared__ int2 stage[CHUNK];        // 32 KB
    __shared__ u16  stb[CHUNK];          // 8 KB
    __shared__ int  hist[512];
    __shared__ int  scanA[512], scanB[512];
    __shared__ int  place[512], runbase[512];
    const int tid = threadIdx.x;
    const int base = blockIdx.x * CHUNK;
    const int nloc = min(CHUNK, E - base);

    for (int i = tid; i < 512; i += 256) hist[i] = 0;
    __syncthreads();
    for (int i = tid; i < nloc; i += 256)
        atomicAdd(&hist[dst[base + i] >> 8], 1);
    __syncthreads();

    // inclusive scan of hist into cur (hist preserved)
    int* cur = hist; int* nxt = scanA; int* other = scanB;
    for (int off = 1; off < 512; off <<= 1) {
        for (int i = tid; i < 512; i += 256)
            nxt[i] = cur[i] + ((i >= off) ? cur[i - off] : 0);
        __syncthreads();
        int* tmp = (cur == hist) ? other : cur;   // after first step ping-pong A<->B
        cur = nxt; nxt = tmp;
    }
    // exclusive scan -> place (mutable) and keep copy in nxt (const xscan)
    int* xscan = nxt;
    for (int i = tid; i < 512; i += 256) {
        int ex = cur[i] - hist[i];
        place[i] = ex;
        xscan[i] = ex;
    }
    __syncthreads();

    // group edges by bucket in LDS
    for (int i = tid; i < nloc; i += 256) {
        int d = dst[base + i];
        int b = d >> 8;
        int pos = atomicAdd(&place[b], 1);
        stage[pos] = make_int2(src[base + i] | ((d & 255) << 24),
                               __float_as_int(w[base + i]));
        stb[pos] = (u16)b;
    }
    __syncthreads();

    // reserve global runs
    for (int i = tid; i < 512; i += 256) {
        int len = hist[i];
        runbase[i] = len ? atomicAdd(&gcursor[i], len) : 0;
    }
    __syncthreads();

    // write out runs (mostly-contiguous bursts)
    for (int i = tid; i < nloc; i += 256) {
        int b = stb[i];
        es[runbase[b] + (i - xscan[b])] = stage[i];
    }
}

// ------- gather1: per bucket, LDS accum + relu(+b1) @ W2 -> h2 bf16 -------
__global__ __launch_bounds__(256, 2) void gather1_kernel(
    const u16* __restrict__ h1, const int2* __restrict__ es,
    const int* __restrict__ boff, const float* __restrict__ b1,
    const float* __restrict__ W2, u16* __restrict__ h2, int N)
{
    __shared__ float acc[256][65];               // 66.6 KB, pad -> 2-way free
    __shared__ __align__(16) float w2s[64][32];  // 8 KB
    __shared__ float b1s[64];
    const int tid = threadIdx.x;

    for (int i = tid; i < 256*65; i += 256) ((float*)acc)[i] = 0.f;
    {
        const float4* s4 = (const float4*)W2;
        float4* d4 = (float4*)&w2s[0][0];
        d4[tid] = s4[tid];
        d4[tid + 256] = s4[tid + 256];
        if (tid < 16) ((float4*)b1s)[tid] = ((const float4*)b1)[tid];
    }
    __syncthreads();

    const int b = blockIdx.x;
    const int e0 = boff[b], e1 = boff[b + 1];
    const int wave = tid >> 6, lane = tid & 63;
    const int len = e1 - e0;
    const int per = (len + 3) >> 2;
    const int s = e0 + wave * per;
    const int eend = min(s + per, e1);

    int p = s;
    for (; p + 4 <= eend; p += 4) {
        int2 ea = es[p], eb = es[p+1], ec = es[p+2], ed = es[p+3];
        float va = bf2f(h1[(size_t)(ea.x & 0xFFFFFF) * 64 + lane]) * __int_as_float(ea.y);
        float vb = bf2f(h1[(size_t)(eb.x & 0xFFFFFF) * 64 + lane]) * __int_as_float(eb.y);
        float vc = bf2f(h1[(size_t)(ec.x & 0xFFFFFF) * 64 + lane]) * __int_as_float(ec.y);
        float vd = bf2f(h1[(size_t)(ed.x & 0xFFFFFF) * 64 + lane]) * __int_as_float(ed.y);
        unsafeAtomicAdd(&acc[(unsigned)ea.x >> 24][lane], va);
        unsafeAtomicAdd(&acc[(unsigned)eb.x >> 24][lane], vb);
        unsafeAtomicAdd(&acc[(unsigned)ec.x >> 24][lane], vc);
        unsafeAtomicAdd(&acc[(unsigned)ed.x >> 24][lane], vd);
    }
    for (; p < eend; p++) {
        int2 ea = es[p];
        float va = bf2f(h1[(size_t)(ea.x & 0xFFFFFF) * 64 + lane]) * __int_as_float(ea.y);
        unsafeAtomicAdd(&acc[(unsigned)ea.x >> 24][lane], va);
    }
    __syncthreads();

    // layer2: node n = tid, t = relu(acc[n]+b1), o = t @ W2
    const int n = tid;
    const int g = b * 256 + n;
    if (g < N) {
        float o[32];
        #pragma unroll
        for (int c = 0; c < 32; c++) o[c] = 0.f;
        #pragma unroll 8
        for (int j = 0; j < 64; j++) {
            float tj = fmaxf(acc[n][j] + b1s[j], 0.f);
            #pragma unroll
            for (int c4 = 0; c4 < 8; c4++) {
                float4 wv = *(const float4*)&w2s[j][c4*4];
                o[c4*4+0] += tj * wv.x;
                o[c4*4+1] += tj * wv.y;
                o[c4*4+2] += tj * wv.z;
                o[c4*4+3] += tj * wv.w;
            }
        }
        u16 ob[32];
        #pragma unroll
        for (int c = 0; c < 32; c++) ob[c] = f2bf(o[c]);
        #pragma unroll
        for (int q = 0; q < 4; q++)
            *(short8*)&h2[(size_t)g * 32 + q*8] = *(const short8*)&ob[q*8];
    }
}

// ------- gather2: per bucket, LDS accum + b2 -> out f32 -------
__global__ __launch_bounds__(256, 4) void gather2_kernel(
    const u16* __restrict__ h2, const int2* __restrict__ es,
    const int* __restrict__ boff, const float* __restrict__ b2,
    float* __restrict__ out, int N)
{
    __shared__ float acc2[256][33];              // 33.8 KB, pad -> conflict-free
    const int tid = threadIdx.x;
    for (int i = tid; i < 256*33; i += 256) ((float*)acc2)[i] = 0.f;
    __syncthreads();

    const int b = blockIdx.x;
    const int e0 = boff[b], e1 = boff[b + 1];
    const int wave = tid >> 6, lane = tid & 63;
    const int half = lane >> 5, f = lane & 31;
    const int len = e1 - e0;
    const int per = (len + 3) >> 2;
    const int s = e0 + wave * per;
    const int eend = min(s + per, e1);

    int p = s;
    for (; p + 4 <= eend; p += 4) {
        int2 ev0 = es[p + half];
        int2 ev1 = es[p + 2 + half];
        float v0 = bf2f(h2[(size_t)(ev0.x & 0xFFFFFF) * 32 + f]) * __int_as_float(ev0.y);
        float v1 = bf2f(h2[(size_t)(ev1.x & 0xFFFFFF) * 32 + f]) * __int_as_float(ev1.y);
        unsafeAtomicAdd(&acc2[(unsigned)ev0.x >> 24][f], v0);
        unsafeAtomicAdd(&acc2[(unsigned)ev1.x >> 24][f], v1);
    }
    for (; p < eend; p += 2) {
        int idx = p + half;
        if (idx < eend) {
            int2 ev = es[idx];
            float v = bf2f(h2[(size_t)(ev.x & 0xFFFFFF) * 32 + f]) * __int_as_float(ev.y);
            unsafeAtomicAdd(&acc2[(unsigned)ev.x >> 24][f], v);
        }
    }
    __syncthreads();

    for (int i = tid; i < 256*32; i += 256) {
        int n = i >> 5, c = i & 31;
        int g = b * 256 + n;
        if (g < N) out[(size_t)g * 32 + c] = acc2[n][c] + b2[c];
    }
}

extern "C" void kernel_launch(void* const* d_in, const int* in_sizes, int n_in,
                              void* d_out, int out_size, void* d_ws, size_t ws_size,
                              hipStream_t stream)
{
    const float* x   = (const float*)d_in[0];
    const int*  esrc = (const int*)d_in[1];
    const int*  edst = (const int*)d_in[2];
    const float* ew  = (const float*)d_in[3];
    const float* W1  = (const float*)d_in[4];
    const float* b1  = (const float*)d_in[5];
    const float* W2  = (const float*)d_in[6];
    const float* b2  = (const float*)d_in[7];
    float* out = (float*)d_out;

    const int N = in_sizes[0] / 128;   // 100000
    const int E = in_sizes[1];         // 1600000
    const int nb = (N + 255) >> 8;     // 391 buckets

    char* base = (char*)d_ws;
    size_t o = 0;
    auto alloc = [&](size_t bytes) { char* p = base + o; o = (o + bytes + 255) & ~(size_t)255; return p; };
    u16*  h1      = (u16*) alloc((size_t)N * 64 * 2);
    u16*  h2      = (u16*) alloc((size_t)N * 32 * 2);
    int2* es      = (int2*)alloc((size_t)E * 8);
    int*  counts  = (int*) alloc(512 * 4);
    int*  boff    = (int*) alloc(512 * 4);
    int*  gcursor = (int*) alloc(512 * 4);

    hipMemsetAsync(counts, 0, 512 * 4, stream);
    g1_mfma<<<(N + 63) / 64, 256, 0, stream>>>(x, W1, h1, N);
    bucket_hist<<<(E + 1023) / 1024, 256, 0, stream>>>(edst, counts, E);
    bucket_scan<<<1, 512, 0, stream>>>(counts, boff, gcursor, nb);
    partition_kernel<<<(E + CHUNK - 1) / CHUNK, 256, 0, stream>>>(esrc, edst, ew, gcursor, es, E);
    gather1_kernel<<<nb, 256, 0, stream>>>(h1, es, boff, b1, W2, h2, N);
    gather2_kernel<<<nb, 256, 0, stream>>>(h2, es, boff, b2, out, N);
}

// Round 5
// 322.768 us; speedup vs baseline: 3.8321x; 3.8321x over previous
//
#include <hip/hip_runtime.h>
#include <hip/hip_bf16.h>

// GCN 2-layer, two-pass dst-radix-sort + per-node wave gathers:
//   h1 = bf16( bf16(x) @ bf16(W1) )     (MFMA 16x16x32, [N,64])
//   pass1: partition edges into buckets of 256 dst (dst>>8), LDS-staged runs
//   pass2: per-bucket counting sort by dst&255 -> es2 (dst-sorted) + off[] per node
//   gather1 (wave/node): t = relu(segsum(h1[src]*w)+b1); h2 = t @ W2 (bf16)
//   gather2 (wave/node): out = segsum(h2[src]*w) + b2   (f32)

typedef unsigned short u16;
typedef short short8 __attribute__((ext_vector_type(8)));
typedef float floatx4 __attribute__((ext_vector_type(4)));

static __device__ __forceinline__ float bf2f(u16 v) {
    return __uint_as_float(((unsigned int)v) << 16);
}
static __device__ __forceinline__ u16 f2bf(float f) {
    unsigned int u = __float_as_uint(f);
    return (u16)((u + 0x7fff + ((u >> 16) & 1)) >> 16);   // RNE
}

#define F4C(v, j) ((j)==0?(v).x:((j)==1?(v).y:((j)==2?(v).z:(v).w)))

// ---------------- g1_mfma: h1 = x @ W1 via bf16 MFMA ----------------
__global__ __launch_bounds__(256, 4) void g1_mfma(
    const float* __restrict__ x, const float* __restrict__ W1,
    u16* __restrict__ h1, int N)
{
    __shared__ __align__(16) u16 xs[64][136];
    __shared__ __align__(16) u16 wf[4][4][64][8];      // [ntile][step][lane][j]
    const int tid  = threadIdx.x;
    const int row0 = blockIdx.x * 64;

    {   // stage W1 (128x64 f32) -> bf16, swizzled to B-fragment order
        const float4* W4 = (const float4*)W1;
        #pragma unroll
        for (int i = 0; i < 8; i++) {
            int idx = tid + i*256;
            int k = idx >> 4, n4 = (idx & 15) * 4;
            float4 v = W4[idx];
            int step = k >> 5, klane = (k >> 3) & 3, j = k & 7;
            #pragma unroll
            for (int c = 0; c < 4; c++) {
                int n = n4 + c;
                wf[n >> 4][step][klane*16 + (n & 15)][j] = f2bf(F4C(v, c));
            }
        }
    }
    {   // stage x tile -> bf16
        const float4* x4 = (const float4*)x;
        #pragma unroll
        for (int i = 0; i < 8; i++) {
            int idx = tid + i*256;
            int r = idx >> 5, kc = idx & 31;
            int gr = row0 + r;
            float4 v = make_float4(0.f,0.f,0.f,0.f);
            if (gr < N) v = x4[gr*32 + kc];
            ushort4 o;
            o.x = f2bf(v.x); o.y = f2bf(v.y); o.z = f2bf(v.z); o.w = f2bf(v.w);
            *(ushort4*)&xs[r][kc*4] = o;
        }
    }
    __syncthreads();

    const int wave = tid >> 6, lane = tid & 63;
    const int m = lane & 15, quad = lane >> 4;
    const int rw = wave * 16;

    floatx4 acc[4] = {(floatx4)(0.f), (floatx4)(0.f), (floatx4)(0.f), (floatx4)(0.f)};
    #pragma unroll
    for (int step = 0; step < 4; step++) {
        short8 a = *(const short8*)&xs[rw + m][step*32 + quad*8];
        #pragma unroll
        for (int nt = 0; nt < 4; nt++) {
            short8 b = *(const short8*)&wf[nt][step][lane][0];
            acc[nt] = __builtin_amdgcn_mfma_f32_16x16x32_bf16(a, b, acc[nt], 0, 0, 0);
        }
    }
    #pragma unroll
    for (int nt = 0; nt < 4; nt++) {
        #pragma unroll
        for (int r = 0; r < 4; r++) {
            int gr = row0 + rw + quad*4 + r;
            if (gr < N) h1[(size_t)gr*64 + nt*16 + m] = f2bf(acc[nt][r]);
        }
    }
}

// ---------------- bucket histogram (LDS pre-aggregated) ----------------
__global__ __launch_bounds__(256) void bucket_hist(
    const int* __restrict__ dst, int* __restrict__ counts, int E)
{
    __shared__ int h[512];
    const int tid = threadIdx.x;
    for (int i = tid; i < 512; i += 256) h[i] = 0;
    __syncthreads();
    int base = blockIdx.x * 1024;
    #pragma unroll
    for (int k = 0; k < 4; k++) {
        int i = base + k*256 + tid;
        if (i < E) atomicAdd(&h[dst[i] >> 8], 1);
    }
    __syncthreads();
    for (int i = tid; i < 512; i += 256)
        if (h[i]) atomicAdd(&counts[i], h[i]);
}

// ---------------- bucket scan (1 block, 512 threads) ----------------
__global__ __launch_bounds__(512) void bucket_scan(
    const int* __restrict__ counts, int* __restrict__ boff,
    int* __restrict__ gcursor, int nb)
{
    __shared__ int A[512], B[512];
    const int t = threadIdx.x;
    int v = (t < nb) ? counts[t] : 0;
    A[t] = v;
    __syncthreads();
    int* cur = A; int* nxt = B;
    for (int off = 1; off < 512; off <<= 1) {
        nxt[t] = cur[t] + ((t >= off) ? cur[t - off] : 0);
        __syncthreads();
        int* tmp = cur; cur = nxt; nxt = tmp;
    }
    int ex = cur[t] - v;           // exclusive
    if (t <= nb) boff[t] = ex;     // boff[nb] == E
    if (t < nb)  gcursor[t] = ex;
}

// ---------------- pass1: LDS-staged scatter into bucket runs ----------
// entry: x = src | (dst&255)<<24 ; y = w bits
#define CHUNK 4096
__global__ __launch_bounds__(256, 3) void partition_kernel(
    const int* __restrict__ src, const int* __restrict__ dst,
    const float* __restrict__ w, int* __restrict__ gcursor,
    int2* __restrict__ es, int E)
{
    __shared__ int2 stage[CHUNK];        // 32 KB
    __shared__ u16  stb[CHUNK];          // 8 KB
    __shared__ int  hist[512];
    __shared__ int  scanA[512], scanB[512];
    __shared__ int  place[512], runbase[512];
    const int tid = threadIdx.x;
    const int base = blockIdx.x * CHUNK;
    const int nloc = min(CHUNK, E - base);

    for (int i = tid; i < 512; i += 256) hist[i] = 0;
    __syncthreads();
    for (int i = tid; i < nloc; i += 256)
        atomicAdd(&hist[dst[base + i] >> 8], 1);
    __syncthreads();

    // inclusive scan of hist into cur (hist preserved)
    int* cur = hist; int* nxt = scanA; int* other = scanB;
    for (int off = 1; off < 512; off <<= 1) {
        for (int i = tid; i < 512; i += 256)
            nxt[i] = cur[i] + ((i >= off) ? cur[i - off] : 0);
        __syncthreads();
        int* tmp = (cur == hist) ? other : cur;
        cur = nxt; nxt = tmp;
    }
    int* xscan = nxt;
    for (int i = tid; i < 512; i += 256) {
        int ex = cur[i] - hist[i];
        place[i] = ex;
        xscan[i] = ex;
    }
    __syncthreads();

    for (int i = tid; i < nloc; i += 256) {
        int d = dst[base + i];
        int b = d >> 8;
        int pos = atomicAdd(&place[b], 1);
        stage[pos] = make_int2(src[base + i] | ((d & 255) << 24),
                               __float_as_int(w[base + i]));
        stb[pos] = (u16)b;
    }
    __syncthreads();

    for (int i = tid; i < 512; i += 256) {
        int len = hist[i];
        runbase[i] = len ? atomicAdd(&gcursor[i], len) : 0;
    }
    __syncthreads();

    for (int i = tid; i < nloc; i += 256) {
        int b = stb[i];
        es[runbase[b] + (i - xscan[b])] = stage[i];
    }
}

// ------- pass2: per-bucket counting sort by dst&255 -> es2 + off[] -------
__global__ __launch_bounds__(256) void sort2_kernel(
    const int2* __restrict__ es, const int* __restrict__ boff,
    int2* __restrict__ es2, int* __restrict__ off, int N, int nb)
{
    __shared__ int hist[256];
    __shared__ int sA[256], sB[256];
    __shared__ int cur[256];
    const int t = threadIdx.x;
    const int b = blockIdx.x;
    const int e0 = boff[b], e1 = boff[b + 1];

    hist[t] = 0;
    __syncthreads();
    for (int i = e0 + t; i < e1; i += 256)
        atomicAdd(&hist[((unsigned)es[i].x) >> 24], 1);
    __syncthreads();

    sA[t] = hist[t];
    __syncthreads();
    int* a = sA; int* bq = sB;
    for (int o = 1; o < 256; o <<= 1) {      // 8 steps -> result back in sA
        bq[t] = a[t] + ((t >= o) ? a[t - o] : 0);
        __syncthreads();
        int* tmp = a; a = bq; bq = tmp;
    }
    int ex = a[t] - hist[t];                 // exclusive within bucket
    cur[t] = ex;
    int g = b * 256 + t;
    if (g < N) off[g] = e0 + ex;
    if (b == nb - 1 && t == 0) off[N] = e1;  // == E
    __syncthreads();

    for (int i = e0 + t; i < e1; i += 256) {
        int2 e = es[i];
        int pos = e0 + atomicAdd(&cur[((unsigned)e.x) >> 24], 1);
        es2[pos] = e;                        // scatter within 32 KB window
    }
}

// ------- gather1 + layer2 fused: wave per dst node, lane = feat -------
__global__ __launch_bounds__(256) void gather1_kernel(
    const u16* __restrict__ h1, const int2* __restrict__ es,
    const int* __restrict__ off, const float* __restrict__ b1,
    const float* __restrict__ W2, u16* __restrict__ h2, int N)
{
    __shared__ __align__(16) float w2s[64][32];
    __shared__ __align__(16) float b1s[64];
    __shared__ float ts[4][64];
    const int tid = threadIdx.x;

    {   // stage W2 (512 float4) + b1
        const float4* s4 = (const float4*)W2;
        float4* d4 = (float4*)&w2s[0][0];
        d4[tid] = s4[tid];
        d4[tid + 256] = s4[tid + 256];
        if (tid < 16) ((float4*)b1s)[tid] = ((const float4*)b1)[tid];
    }
    __syncthreads();

    const int wave = tid >> 6, lane = tid & 63;
    const int d = blockIdx.x * 4 + wave;
    if (d >= N) return;   // wave-uniform exit, after the only __syncthreads

    int pbeg = __builtin_amdgcn_readfirstlane(off[d]);
    int pend = __builtin_amdgcn_readfirstlane(off[d + 1]);

    float acc = 0.f;
    int p = pbeg;
    for (; p + 3 < pend; p += 4) {
        int2 e0 = es[p], e1 = es[p+1], e2 = es[p+2], e3 = es[p+3];
        acc += bf2f(h1[(size_t)(e0.x & 0xFFFFFF) * 64 + lane]) * __int_as_float(e0.y)
             + bf2f(h1[(size_t)(e1.x & 0xFFFFFF) * 64 + lane]) * __int_as_float(e1.y)
             + bf2f(h1[(size_t)(e2.x & 0xFFFFFF) * 64 + lane]) * __int_as_float(e2.y)
             + bf2f(h1[(size_t)(e3.x & 0xFFFFFF) * 64 + lane]) * __int_as_float(e3.y);
    }
    for (; p < pend; p++) {
        int2 e0 = es[p];
        acc += bf2f(h1[(size_t)(e0.x & 0xFFFFFF) * 64 + lane]) * __int_as_float(e0.y);
    }
    float t = fmaxf(acc + b1s[lane], 0.f);
    ts[wave][lane] = t;
    // intra-wave LDS write->read: in-order wave issue + compiler lgkmcnt

    const int c = lane & 31, half = lane >> 5;
    float part = 0.f;
    #pragma unroll
    for (int j = 0; j < 32; j++) {
        part += ts[wave][half * 32 + j] * w2s[half * 32 + j][c];
    }
    part += __shfl_xor(part, 32, 64);
    if (half == 0) h2[(size_t)d * 32 + c] = f2bf(part);
}

// ------- gather2: out = segsum(h2[src]*w) + b2, wave per node -------
__global__ __launch_bounds__(256) void gather2_kernel(
    const u16* __restrict__ h2, const int2* __restrict__ es,
    const int* __restrict__ off, const float* __restrict__ b2,
    float* __restrict__ out, int N)
{
    const int tid = threadIdx.x;
    const int wave = tid >> 6, lane = tid & 63;
    const int d = blockIdx.x * 4 + wave;
    if (d >= N) return;
    const int c = lane & 31, half = lane >> 5;

    int pbeg = __builtin_amdgcn_readfirstlane(off[d]);
    int pend = __builtin_amdgcn_readfirstlane(off[d + 1]);

    float acc = (half == 0) ? b2[c] : 0.f;
    int p = pbeg + half;
    for (; p + 2 < pend; p += 4) {
        int2 ea = es[p], eb = es[p + 2];
        acc += bf2f(h2[(size_t)(ea.x & 0xFFFFFF) * 32 + c]) * __int_as_float(ea.y)
             + bf2f(h2[(size_t)(eb.x & 0xFFFFFF) * 32 + c]) * __int_as_float(eb.y);
    }
    if (p < pend) {
        int2 ea = es[p];
        acc += bf2f(h2[(size_t)(ea.x & 0xFFFFFF) * 32 + c]) * __int_as_float(ea.y);
    }
    acc += __shfl_xor(acc, 32, 64);
    if (half == 0) out[(size_t)d * 32 + c] = acc;
}

extern "C" void kernel_launch(void* const* d_in, const int* in_sizes, int n_in,
                              void* d_out, int out_size, void* d_ws, size_t ws_size,
                              hipStream_t stream)
{
    const float* x   = (const float*)d_in[0];
    const int*  esrc = (const int*)d_in[1];
    const int*  edst = (const int*)d_in[2];
    const float* ew  = (const float*)d_in[3];
    const float* W1  = (const float*)d_in[4];
    const float* b1  = (const float*)d_in[5];
    const float* W2  = (const float*)d_in[6];
    const float* b2  = (const float*)d_in[7];
    float* out = (float*)d_out;

    const int N = in_sizes[0] / 128;   // 100000
    const int E = in_sizes[1];         // 1600000
    const int nb = (N + 255) >> 8;     // 391 buckets

    char* base = (char*)d_ws;
    size_t o = 0;
    auto alloc = [&](size_t bytes) { char* p = base + o; o = (o + bytes + 255) & ~(size_t)255; return p; };
    u16*  h1      = (u16*) alloc((size_t)N * 64 * 2);
    u16*  h2      = (u16*) alloc((size_t)N * 32 * 2);
    int2* es      = (int2*)alloc((size_t)E * 8);
    int2* es2     = (int2*)alloc((size_t)E * 8);
    int*  off     = (int*) alloc((size_t)(N + 1) * 4);
    int*  counts  = (int*) alloc(512 * 4);
    int*  boff    = (int*) alloc(512 * 4);
    int*  gcursor = (int*) alloc(512 * 4);

    hipMemsetAsync(counts, 0, 512 * 4, stream);
    g1_mfma<<<(N + 63) / 64, 256, 0, stream>>>(x, W1, h1, N);
    bucket_hist<<<(E + 1023) / 1024, 256, 0, stream>>>(edst, counts, E);
    bucket_scan<<<1, 512, 0, stream>>>(counts, boff, gcursor, nb);
    partition_kernel<<<(E + CHUNK - 1) / CHUNK, 256, 0, stream>>>(esrc, edst, ew, gcursor, es, E);
    sort2_kernel<<<nb, 256, 0, stream>>>(es, boff, es2, off, N, nb);
    gather1_kernel<<<(N + 3) / 4, 256, 0, stream>>>(h1, es2, off, b1, W2, h2, N);
    gather2_kernel<<<(N + 3) / 4, 256, 0, stream>>>(h2, es2, off, b2, out, N);
}

// Round 6
// 294.247 us; speedup vs baseline: 4.2036x; 1.0969x over previous
//
#include <hip/hip_runtime.h>
#include <hip/hip_bf16.h>

// GCN 2-layer, two-pass dst-radix-sort + per-node wave gathers:
//   h1 = bf16( bf16(x) @ bf16(W1) )     (MFMA 16x16x32, [N,64])
//   pass1: partition edges into buckets of 256 dst (dst>>8), LDS-staged runs
//   pass2: per-bucket counting sort by dst&255 -> es2 (dst-sorted) + off[] per node
//   gather1 (wave/node, 2 feats/lane): t = relu(segsum(h1[src]*w)+b1); h2 = t @ W2
//   gather2 (wave/node, 16 lanes/edge): out = segsum(h2[src]*w) + b2 (f32)

typedef unsigned short u16;
typedef unsigned int uint;
typedef short short8 __attribute__((ext_vector_type(8)));
typedef float floatx4 __attribute__((ext_vector_type(4)));

static __device__ __forceinline__ float bf2f(u16 v) {
    return __uint_as_float(((unsigned int)v) << 16);
}
static __device__ __forceinline__ u16 f2bf(float f) {
    unsigned int u = __float_as_uint(f);
    return (u16)((u + 0x7fff + ((u >> 16) & 1)) >> 16);   // RNE
}

#define F4C(v, j) ((j)==0?(v).x:((j)==1?(v).y:((j)==2?(v).z:(v).w)))

// ---------------- g1_mfma: h1 = x @ W1 via bf16 MFMA ----------------
__global__ __launch_bounds__(256, 4) void g1_mfma(
    const float* __restrict__ x, const float* __restrict__ W1,
    u16* __restrict__ h1, int N)
{
    __shared__ __align__(16) u16 xs[64][136];
    __shared__ __align__(16) u16 wf[4][4][64][8];      // [ntile][step][lane][j]
    const int tid  = threadIdx.x;
    const int row0 = blockIdx.x * 64;

    {   // stage W1 (128x64 f32) -> bf16, swizzled to B-fragment order
        const float4* W4 = (const float4*)W1;
        #pragma unroll
        for (int i = 0; i < 8; i++) {
            int idx = tid + i*256;
            int k = idx >> 4, n4 = (idx & 15) * 4;
            float4 v = W4[idx];
            int step = k >> 5, klane = (k >> 3) & 3, j = k & 7;
            #pragma unroll
            for (int c = 0; c < 4; c++) {
                int n = n4 + c;
                wf[n >> 4][step][klane*16 + (n & 15)][j] = f2bf(F4C(v, c));
            }
        }
    }
    {   // stage x tile -> bf16
        const float4* x4 = (const float4*)x;
        #pragma unroll
        for (int i = 0; i < 8; i++) {
            int idx = tid + i*256;
            int r = idx >> 5, kc = idx & 31;
            int gr = row0 + r;
            float4 v = make_float4(0.f,0.f,0.f,0.f);
            if (gr < N) v = x4[gr*32 + kc];
            ushort4 o;
            o.x = f2bf(v.x); o.y = f2bf(v.y); o.z = f2bf(v.z); o.w = f2bf(v.w);
            *(ushort4*)&xs[r][kc*4] = o;
        }
    }
    __syncthreads();

    const int wave = tid >> 6, lane = tid & 63;
    const int m = lane & 15, quad = lane >> 4;
    const int rw = wave * 16;

    floatx4 acc[4] = {(floatx4)(0.f), (floatx4)(0.f), (floatx4)(0.f), (floatx4)(0.f)};
    #pragma unroll
    for (int step = 0; step < 4; step++) {
        short8 a = *(const short8*)&xs[rw + m][step*32 + quad*8];
        #pragma unroll
        for (int nt = 0; nt < 4; nt++) {
            short8 b = *(const short8*)&wf[nt][step][lane][0];
            acc[nt] = __builtin_amdgcn_mfma_f32_16x16x32_bf16(a, b, acc[nt], 0, 0, 0);
        }
    }
    #pragma unroll
    for (int nt = 0; nt < 4; nt++) {
        #pragma unroll
        for (int r = 0; r < 4; r++) {
            int gr = row0 + rw + quad*4 + r;
            if (gr < N) h1[(size_t)gr*64 + nt*16 + m] = f2bf(acc[nt][r]);
        }
    }
}

// ---------------- bucket histogram (LDS pre-aggregated) ----------------
__global__ __launch_bounds__(256) void bucket_hist(
    const int* __restrict__ dst, int* __restrict__ counts, int E)
{
    __shared__ int h[512];
    const int tid = threadIdx.x;
    for (int i = tid; i < 512; i += 256) h[i] = 0;
    __syncthreads();
    int base = blockIdx.x * 1024;
    #pragma unroll
    for (int k = 0; k < 4; k++) {
        int i = base + k*256 + tid;
        if (i < E) atomicAdd(&h[dst[i] >> 8], 1);
    }
    __syncthreads();
    for (int i = tid; i < 512; i += 256)
        if (h[i]) atomicAdd(&counts[i], h[i]);
}

// ---------------- bucket scan (1 block, 512 threads) ----------------
__global__ __launch_bounds__(512) void bucket_scan(
    const int* __restrict__ counts, int* __restrict__ boff,
    int* __restrict__ gcursor, int nb)
{
    __shared__ int A[512], B[512];
    const int t = threadIdx.x;
    int v = (t < nb) ? counts[t] : 0;
    A[t] = v;
    __syncthreads();
    int* cur = A; int* nxt = B;
    for (int off = 1; off < 512; off <<= 1) {
        nxt[t] = cur[t] + ((t >= off) ? cur[t - off] : 0);
        __syncthreads();
        int* tmp = cur; cur = nxt; nxt = tmp;
    }
    int ex = cur[t] - v;           // exclusive
    if (t <= nb) boff[t] = ex;     // boff[nb] == E
    if (t < nb)  gcursor[t] = ex;
}

// ---------------- pass1: LDS-staged scatter into bucket runs ----------
// entry: x = src | (dst&255)<<24 ; y = w bits
#define CHUNK 4096
#define PT 512
__global__ __launch_bounds__(512, 2) void partition_kernel(
    const int* __restrict__ src, const int* __restrict__ dst,
    const float* __restrict__ w, int* __restrict__ gcursor,
    int2* __restrict__ es, int E)
{
    __shared__ int2 stage[CHUNK];        // 32 KB
    __shared__ u16  stb[CHUNK];          // 8 KB
    __shared__ int  hist[512];
    __shared__ int  sc[512];
    __shared__ int  xscan[512], place[512], runbase[512];
    const int tid = threadIdx.x;
    const int base = blockIdx.x * CHUNK;
    const int nloc = min(CHUNK, E - base);

    hist[tid] = 0;
    __syncthreads();
    for (int i = tid; i < nloc; i += PT)
        atomicAdd(&hist[dst[base + i] >> 8], 1);
    __syncthreads();

    int v = hist[tid];
    sc[tid] = v;
    __syncthreads();
    for (int o = 1; o < 512; o <<= 1) {          // Hillis-Steele inclusive
        int add = (tid >= o) ? sc[tid - o] : 0;
        __syncthreads();
        sc[tid] += add;
        __syncthreads();
    }
    int ex = sc[tid] - v;
    xscan[tid] = ex;
    place[tid] = ex;
    __syncthreads();

    for (int i = tid; i < nloc; i += PT) {
        int d = dst[base + i];
        int b = d >> 8;
        int pos = atomicAdd(&place[b], 1);
        stage[pos] = make_int2(src[base + i] | ((d & 255) << 24),
                               __float_as_int(w[base + i]));
        stb[pos] = (u16)b;
    }
    __syncthreads();

    runbase[tid] = hist[tid] ? atomicAdd(&gcursor[tid], hist[tid]) : 0;
    __syncthreads();

    for (int i = tid; i < nloc; i += PT) {
        int b = stb[i];
        es[runbase[b] + (i - xscan[b])] = stage[i];
    }
}

// ------- pass2: per-bucket counting sort by dst&255 -> es2 + off[] -------
__global__ __launch_bounds__(512) void sort2_kernel(
    const int2* __restrict__ es, const int* __restrict__ boff,
    int2* __restrict__ es2, int* __restrict__ off, int N, int nb)
{
    __shared__ int hist[256], sc[256], cur[256];
    const int t = threadIdx.x;
    const int b = blockIdx.x;
    const int e0 = boff[b], e1 = boff[b + 1];

    if (t < 256) hist[t] = 0;
    __syncthreads();
    for (int i = e0 + t; i < e1; i += 512)
        atomicAdd(&hist[((unsigned)es[i].x) >> 24], 1);
    __syncthreads();

    int v = 0;
    if (t < 256) { v = hist[t]; sc[t] = v; }
    __syncthreads();
    for (int o = 1; o < 256; o <<= 1) {
        int add = 0;
        if (t < 256 && t >= o) add = sc[t - o];
        __syncthreads();
        if (t < 256) sc[t] += add;
        __syncthreads();
    }
    if (t < 256) {
        int ex = sc[t] - v;                  // exclusive within bucket
        cur[t] = ex;
        int g = b * 256 + t;
        if (g < N) off[g] = e0 + ex;
        if (b == nb - 1 && t == 0) off[N] = e1;   // == E
    }
    __syncthreads();

    for (int i = e0 + t; i < e1; i += 512) {
        int2 e = es[i];
        int pos = e0 + atomicAdd(&cur[((unsigned)e.x) >> 24], 1);
        es2[pos] = e;                        // scatter within 32 KB window
    }
}

// ------- gather1 + layer2 fused: wave/node, 32 lanes/edge (2 feats/lane) ----
__global__ __launch_bounds__(256) void gather1_kernel(
    const u16* __restrict__ h1, const int2* __restrict__ es,
    const int* __restrict__ off, const float* __restrict__ b1,
    const float* __restrict__ W2, u16* __restrict__ h2, int N)
{
    __shared__ __align__(16) float w2s[64][32];
    __shared__ __align__(16) float b1s[64];
    __shared__ float ts[4][64];
    const int tid = threadIdx.x;

    {   // stage W2 (512 float4) + b1
        const float4* s4 = (const float4*)W2;
        float4* d4 = (float4*)&w2s[0][0];
        d4[tid] = s4[tid];
        d4[tid + 256] = s4[tid + 256];
        if (tid < 16) ((float4*)b1s)[tid] = ((const float4*)b1)[tid];
    }
    __syncthreads();

    const int wave = tid >> 6, lane = tid & 63;
    const int d = blockIdx.x * 4 + wave;
    if (d >= N) return;   // wave-uniform exit, after the only __syncthreads
    const int h = lane >> 5, fl = lane & 31;

    int pbeg = __builtin_amdgcn_readfirstlane(off[d]);
    int pend = __builtin_amdgcn_readfirstlane(off[d + 1]);

    const uint* h1u = (const uint*)h1;     // h1 row = 32 uints (64 bf16)
    float ax = 0.f, ay = 0.f;
    int p = pbeg;
    for (; p + 8 <= pend; p += 8) {        // 8 edges/iter, 4 gathers in flight
        int2 e0 = es[p + h],     e1 = es[p + 2 + h];
        int2 e2 = es[p + 4 + h], e3 = es[p + 6 + h];
        uint v0 = h1u[(size_t)(e0.x & 0xFFFFFF) * 32 + fl];
        uint v1 = h1u[(size_t)(e1.x & 0xFFFFFF) * 32 + fl];
        uint v2 = h1u[(size_t)(e2.x & 0xFFFFFF) * 32 + fl];
        uint v3 = h1u[(size_t)(e3.x & 0xFFFFFF) * 32 + fl];
        float w0 = __int_as_float(e0.y), w1 = __int_as_float(e1.y);
        float w2 = __int_as_float(e2.y), w3 = __int_as_float(e3.y);
        ax += __uint_as_float(v0 << 16) * w0 + __uint_as_float(v1 << 16) * w1
            + __uint_as_float(v2 << 16) * w2 + __uint_as_float(v3 << 16) * w3;
        ay += __uint_as_float(v0 & 0xFFFF0000u) * w0 + __uint_as_float(v1 & 0xFFFF0000u) * w1
            + __uint_as_float(v2 & 0xFFFF0000u) * w2 + __uint_as_float(v3 & 0xFFFF0000u) * w3;
    }
    for (; p < pend; p += 2) {
        if (p + h < pend) {
            int2 e = es[p + h];
            uint v = h1u[(size_t)(e.x & 0xFFFFFF) * 32 + fl];
            float w = __int_as_float(e.y);
            ax += __uint_as_float(v << 16) * w;
            ay += __uint_as_float(v & 0xFFFF0000u) * w;
        }
    }
    ax += __shfl_xor(ax, 32, 64);
    ay += __shfl_xor(ay, 32, 64);

    float tx = fmaxf(ax + b1s[2*fl],     0.f);
    float ty = fmaxf(ay + b1s[2*fl + 1], 0.f);
    if (h == 0) *(float2*)&ts[wave][2*fl] = make_float2(tx, ty);
    // intra-wave LDS write->read: in-order wave issue + compiler lgkmcnt

    const int c = fl;
    float part = 0.f;
    #pragma unroll
    for (int j = 0; j < 32; j++)
        part += ts[wave][h * 32 + j] * w2s[h * 32 + j][c];
    part += __shfl_xor(part, 32, 64);
    if (h == 0) h2[(size_t)d * 32 + c] = f2bf(part);
}

// ------- gather2: wave/node, 16 lanes/edge (2 feats/lane), out f32 -------
__global__ __launch_bounds__(256) void gather2_kernel(
    const u16* __restrict__ h2, const int2* __restrict__ es,
    const int* __restrict__ off, const float* __restrict__ b2,
    float* __restrict__ out, int N)
{
    const int tid = threadIdx.x;
    const int wave = tid >> 6, lane = tid & 63;
    const int d = blockIdx.x * 4 + wave;
    if (d >= N) return;
    const int q = lane >> 4, fl = lane & 15;

    int pbeg = __builtin_amdgcn_readfirstlane(off[d]);
    int pend = __builtin_amdgcn_readfirstlane(off[d + 1]);

    const uint* h2u = (const uint*)h2;     // h2 row = 16 uints (32 bf16)
    float ax = 0.f, ay = 0.f;
    int p = pbeg;
    for (; p + 8 <= pend; p += 8) {        // 8 edges/iter, 2 gathers/lane
        int2 ea = es[p + q], eb = es[p + 4 + q];
        uint va = h2u[(size_t)(ea.x & 0xFFFFFF) * 16 + fl];
        uint vb = h2u[(size_t)(eb.x & 0xFFFFFF) * 16 + fl];
        float wa = __int_as_float(ea.y), wb = __int_as_float(eb.y);
        ax += __uint_as_float(va << 16) * wa + __uint_as_float(vb << 16) * wb;
        ay += __uint_as_float(va & 0xFFFF0000u) * wa + __uint_as_float(vb & 0xFFFF0000u) * wb;
    }
    for (; p < pend; p += 4) {
        if (p + q < pend) {
            int2 e = es[p + q];
            uint v = h2u[(size_t)(e.x & 0xFFFFFF) * 16 + fl];
            float w = __int_as_float(e.y);
            ax += __uint_as_float(v << 16) * w;
            ay += __uint_as_float(v & 0xFFFF0000u) * w;
        }
    }
    ax += __shfl_xor(ax, 16, 64); ay += __shfl_xor(ay, 16, 64);
    ax += __shfl_xor(ax, 32, 64); ay += __shfl_xor(ay, 32, 64);
    if (q == 0) {
        float2 bb = *(const float2*)&b2[2 * fl];
        *(float2*)&out[(size_t)d * 32 + 2 * fl] = make_float2(ax + bb.x, ay + bb.y);
    }
}

extern "C" void kernel_launch(void* const* d_in, const int* in_sizes, int n_in,
                              void* d_out, int out_size, void* d_ws, size_t ws_size,
                              hipStream_t stream)
{
    const float* x   = (const float*)d_in[0];
    const int*  esrc = (const int*)d_in[1];
    const int*  edst = (const int*)d_in[2];
    const float* ew  = (const float*)d_in[3];
    const float* W1  = (const float*)d_in[4];
    const float* b1  = (const float*)d_in[5];
    const float* W2  = (const float*)d_in[6];
    const float* b2  = (const float*)d_in[7];
    float* out = (float*)d_out;

    const int N = in_sizes[0] / 128;   // 100000
    const int E = in_sizes[1];         // 1600000
    const int nb = (N + 255) >> 8;     // 391 buckets

    char* base = (char*)d_ws;
    size_t o = 0;
    auto alloc = [&](size_t bytes) { char* p = base + o; o = (o + bytes + 255) & ~(size_t)255; return p; };
    u16*  h1      = (u16*) alloc((size_t)N * 64 * 2);
    u16*  h2      = (u16*) alloc((size_t)N * 32 * 2);
    int2* es      = (int2*)alloc((size_t)E * 8);
    int2* es2     = (int2*)alloc((size_t)E * 8);
    int*  off     = (int*) alloc((size_t)(N + 1) * 4);
    int*  counts  = (int*) alloc(512 * 4);
    int*  boff    = (int*) alloc(512 * 4);
    int*  gcursor = (int*) alloc(512 * 4);

    hipMemsetAsync(counts, 0, 512 * 4, stream);
    g1_mfma<<<(N + 63) / 64, 256, 0, stream>>>(x, W1, h1, N);
    bucket_hist<<<(E + 1023) / 1024, 256, 0, stream>>>(edst, counts, E);
    bucket_scan<<<1, 512, 0, stream>>>(counts, boff, gcursor, nb);
    partition_kernel<<<(E + CHUNK - 1) / CHUNK, 512, 0, stream>>>(esrc, edst, ew, gcursor, es, E);
    sort2_kernel<<<nb, 512, 0, stream>>>(es, boff, es2, off, N, nb);
    gather1_kernel<<<(N + 3) / 4, 256, 0, stream>>>(h1, es2, off, b1, W2, h2, N);
    gather2_kernel<<<(N + 3) / 4, 256, 0, stream>>>(h2, es2, off, b2, out, N);
}